// Round 17
// baseline (168.743 us; speedup 1.0000x reference)
//
#include <hip/hip_runtime.h>
#include <cstdint>

// Problem constants
#define NB 4
#define NSEQ 1024
#define NH 16
#define HD 72
#define HID 1152
#define QKV3 3456
#define DP 96           // padded head dim (multiple of 32 for K=32 MFMA)
// scale = 72^-0.5 folded with log2(e) so softmax runs in exp2 domain
#define QSCALE 0.17003713711193175f

typedef __attribute__((ext_vector_type(8))) __bf16 bf16x8;
typedef __attribute__((ext_vector_type(4))) __bf16 bf16x4;
typedef __attribute__((ext_vector_type(4))) float f32x4;

#define AS1 __attribute__((address_space(1)))
#define AS3 __attribute__((address_space(3)))

__device__ __forceinline__ void gl_lds16(const void* g, void* l) {
    // async global->LDS, 16B per lane; LDS dest = wave-uniform base + lane*16
    __builtin_amdgcn_global_load_lds((const AS1 uint32_t*)g, (AS3 uint32_t*)l, 16, 0, 0);
}

// raw barrier: no compiler-inserted vmcnt(0) drain (unlike __syncthreads)
#define RAW_BAR() asm volatile("s_barrier" ::: "memory")

// bare hardware 2^x (single v_exp_f32; libm exp2f is a multi-instr fixup seq)
__device__ __forceinline__ float fast_exp2(float x) {
    float r;
    asm("v_exp_f32 %0, %1" : "=v"(r) : "v"(x));
    return r;
}

// Workspace layout (bytes)
#define XB_OFF     0UL           // x as bf16 [4096][1152]; ALIASED as atto after gemm_qkv
#define WQKVT_OFF  9437184UL     // w_qkv^T bf16  [3584][1152] (rows 3456+ junk, unused)
#define WOUTT_OFF  17694720UL    // w_out^T bf16  [1280][1152] (rows 1152+ junk, unused)
#define QP_OFF     20643840UL    // Q padded bf16 [64][1024][96] (QSCALE folded)
#define KP_OFF     33226752UL    // K padded bf16 [64][1024][96]
#define VT_OFF     45809664UL    // V^T padded bf16 [64][96][1024]
// total: 58,392,576 bytes

// ---------------- fused prep kernel ----------------
// blocks [0,4608):      x fp32 -> bf16 (float4/thread)
// blocks [4608,8496):   w_qkv [1152][3456] -> wqkvT bf16 (32x32 tiles)
// blocks [8496,9792):   w_out [1152][1152] -> woutT bf16
// blocks [9792,10688):  zero d=72..95 pad regions of Qp/Kp/Vt

__global__ void prep_kernel(const float* __restrict__ x, __bf16* __restrict__ xb,
                            const float* __restrict__ w_qkv, __bf16* __restrict__ wqkvT,
                            const float* __restrict__ w_out, __bf16* __restrict__ woutT,
                            __bf16* __restrict__ Qp, __bf16* __restrict__ Kp,
                            __bf16* __restrict__ Vt) {
    __shared__ float t[32][33];
    const int blk = blockIdx.x, tid = threadIdx.x;
    if (blk < 4608) {
        long i = (long)blk * 256 + tid;
        float4 v = ((const float4*)x)[i];
        bf16x4 o = { (__bf16)v.x, (__bf16)v.y, (__bf16)v.z, (__bf16)v.w };
        ((bf16x4*)xb)[i] = o;
    } else if (blk < 9792) {
        const float* in;  __bf16* outp;  int Nc, K, n0, k0;
        if (blk < 8496) {
            int b = blk - 4608; in = w_qkv; outp = wqkvT; Nc = QKV3; K = HID;
            n0 = (b % 108) * 32; k0 = (b / 108) * 32;
        } else {
            int b = blk - 8496; in = w_out; outp = woutT; Nc = HID; K = HID;
            n0 = (b % 36) * 32; k0 = (b / 36) * 32;
        }
        int xx = tid & 31, yy = tid >> 5;
        #pragma unroll
        for (int i = 0; i < 32; i += 8)
            t[yy + i][xx] = in[(long)(k0 + yy + i) * Nc + n0 + xx];
        __syncthreads();
        #pragma unroll
        for (int i = 0; i < 32; i += 8)
            outp[(long)(n0 + yy + i) * K + k0 + xx] = (__bf16)t[xx][yy + i];
    } else {
        int i = (blk - 9792) * 256 + tid;            // 0..229375
        uint4 z = make_uint4(0u, 0u, 0u, 0u);
        if (i < 131072) {
            __bf16* base = (i & 65536) ? Kp : Qp;
            int row = i & 65535;
            uint4* p = (uint4*)(base + row * 96 + 72);   // 48 B pad per row
            p[0] = z; p[1] = z; p[2] = z;
        } else {
            int j = i - 131072;                          // 0..98303
            int bh = j / 1536, w = j - bh * 1536;
            *((uint4*)(Vt + (long)bh * 98304 + 73728) + w) = z;
        }
    }
}

// ---------------- GEMM engine v3: B-frags from L2 to registers, A via LDS ----------------
// r14 diagnosis: old core LDS-read-BW-bound (128 KB/CU/tile-step vs ~85-128
// B/cyc port). r15 retry failed ONLY because launch_bounds(512,6) capped VGPR
// at ~85 -> accumulator spill (VGPR 40, 602 MB scratch). This version keeps
// launch_bounds(512,4): ~106 live VGPRs fit the 128 budget.
// A: triple-buffered LDS via global_load_lds (1 op/thread/tile), T2 swizzle.
// B: 4 bf16x8 register loads from the L2-resident weight panel (coalesced,
// 4 lanes/64B line), issued for t+1 after this tile's MFMAs.
// Barrier ledger (outstanding at wait: [A(t+1), B(t+1)x4, A(t+2)]):
// vmcnt(5) drains ONLY A(t+1) -- the one thing the s_barrier must guarantee
// (shared LDS). B is private registers; the compiler's auto-waitcnt before
// first use covers it, hidden under af-reads + other waves.

template<int MT>   // m-fragments per wave; BM = MT*32 (4 -> 128)
__device__ __forceinline__ void gemm_core(
    const __bf16* __restrict__ A, const __bf16* __restrict__ Bt,
    int lda, int ldb, int ntk, long rowA0, long rowB0,
    char* lds, f32x4 acc[MT][4])
{
    constexpr int BM    = MT * 32;
    constexpr int ATILE = BM * 64;        // 8192 B for BM=128

    const int tid  = threadIdx.x;
    const int wave = tid >> 6, lane = tid & 63;
    const int wm = wave >> 2, wn = wave & 3;      // 2 x 4 wave grid
    const int lhi = lane >> 4, llo = lane & 15;
    const int srow = tid >> 2;                    // staging row (0..127)
    const int scol = (tid & 3) * 8;               // staging col element

    // A staging: one gl_lds per thread per tile, pre-swizzled source
    const int ksw = scol ^ ((((unsigned)srow >> 1) & 3) << 3);
    const __bf16* aSrc = A + (rowA0 + srow) * (long)lda + ksw;
    const int aDst = tid * 16;

    // A fragment byte-offsets (loop-invariant)
    int boffA[MT];
    #pragma unroll
    for (int mt = 0; mt < MT; ++mt) {
        int R = wm * (BM / 2) + mt * 16 + llo;
        boffA[mt] = (R * 64 + lhi * 16) ^ ((((unsigned)R >> 1) & 3) << 4);
    }
    // B fragment global bases
    const __bf16* bp[4];
    #pragma unroll
    for (int nt = 0; nt < 4; ++nt) {
        int R = wn * 64 + nt * 16 + llo;
        bp[nt] = Bt + (rowB0 + R) * (long)ldb + lhi * 8;
    }

    bf16x8 Bc[4];

    // prologue: A(0)->buf0, B(0)->regs, A(1)->buf1; drain all once
    gl_lds16(aSrc, lds + aDst);
    #pragma unroll
    for (int nt = 0; nt < 4; ++nt) Bc[nt] = *(const bf16x8*)(bp[nt]);
    gl_lds16(aSrc + 32, lds + ATILE + aDst);
    asm volatile("s_waitcnt vmcnt(0)" ::: "memory");
    RAW_BAR();

    int buf = 0;
    #pragma unroll 1
    for (int t = 0; t < ntk; ++t) {
        char* Ab = lds + buf * ATILE;
        int nb = buf + 2; if (nb >= 3) nb -= 3;

        bf16x8 af[MT / 2];
        #pragma unroll
        for (int mt = 0; mt < MT / 2; ++mt)
            af[mt] = *(const bf16x8*)(Ab + boffA[mt]);
        __builtin_amdgcn_s_setprio(1);
        #pragma unroll
        for (int mt = 0; mt < MT / 2; ++mt)
            #pragma unroll
            for (int nt = 0; nt < 4; ++nt)
                acc[mt][nt] = __builtin_amdgcn_mfma_f32_16x16x32_bf16(af[mt], Bc[nt], acc[mt][nt], 0, 0, 0);
        __builtin_amdgcn_s_setprio(0);
        #pragma unroll
        for (int mt = 0; mt < MT / 2; ++mt)
            af[mt] = *(const bf16x8*)(Ab + boffA[MT / 2 + mt]);
        __builtin_amdgcn_s_setprio(1);
        #pragma unroll
        for (int mt = 0; mt < MT / 2; ++mt)
            #pragma unroll
            for (int nt = 0; nt < 4; ++nt)
                acc[MT / 2 + mt][nt] = __builtin_amdgcn_mfma_f32_16x16x32_bf16(af[mt], Bc[nt], acc[MT / 2 + mt][nt], 0, 0, 0);
        __builtin_amdgcn_s_setprio(0);

        // issue next-tile operands (old Bc dead after MFMAs -> same regs reload)
        if (t + 1 < ntk) {
            #pragma unroll
            for (int nt = 0; nt < 4; ++nt)
                Bc[nt] = *(const bf16x8*)(bp[nt] + (t + 1) * 32);
        }
        if (t + 2 < ntk) gl_lds16(aSrc + (t + 2) * 32, lds + nb * ATILE + aDst);

        // drain only A(t+1) before the barrier; B(t+1)/A(t+2) stay in flight
        if (t + 2 < ntk)      asm volatile("s_waitcnt vmcnt(5)" ::: "memory");
        else if (t + 1 < ntk) asm volatile("s_waitcnt vmcnt(4)" ::: "memory");
        RAW_BAR();
        buf = (buf == 2) ? 0 : buf + 1;
    }
}

// ---------------- GEMM 1: qkv = x @ w_qkv + b, scatter to Qp/Kp/Vt ----------------
// BM=128: grid 448 blocks (32 M-tiles x 14 N-tiles, N padded 3456->3584)

__global__ __launch_bounds__(512, 4) void gemm_qkv_kernel(
    const __bf16* __restrict__ xb, const __bf16* __restrict__ wqkvT,
    const float* __restrict__ b_qkv,
    __bf16* __restrict__ Qp, __bf16* __restrict__ Kp, __bf16* __restrict__ Vt)
{
    __shared__ char lds[24576];
    f32x4 acc[4][4];
    #pragma unroll
    for (int i = 0; i < 4; ++i)
        #pragma unroll
        for (int j = 0; j < 4; ++j) acc[i][j] = (f32x4){0.f, 0.f, 0.f, 0.f};

    // bijective 2D-chunked XCD swizzle: each XCD owns an 8bx x 7by rectangle
    int lin = blockIdx.x;
    int xcd = lin & 7, l = lin >> 3;              // l in [0,56)
    int lbx = l / 7;
    int bx  = (xcd & 3) * 8 + lbx;                // 0..31
    int by  = (xcd >> 2) * 7 + (l - lbx * 7);     // 0..13
    long rowA0 = (long)bx * 128, rowB0 = (long)by * 256;

    gemm_core<4>(xb, wqkvT, HID, HID, HID / 32, rowA0, rowB0, lds, acc);

    const int wave = threadIdx.x >> 6, lane = threadIdx.x & 63;
    const int wm = wave >> 2, wn = wave & 3, lhi = lane >> 4, llo = lane & 15;

    #pragma unroll
    for (int nt = 0; nt < 4; ++nt) {
        int n = (int)rowB0 + wn * 64 + nt * 16 + llo;   // 0..3583
        if (n >= QKV3) continue;
        int sec = n / HID;
        int nn  = n - sec * HID;
        int h   = nn / HD;
        int d   = nn - h * HD;
        float bias = b_qkv[n];
        if (sec == 2) {
            // V: r-quad is nq-contiguous -> one 8B bf16x4 store per mt
            #pragma unroll
            for (int mt = 0; mt < 4; ++mt) {
                int m0 = (int)rowA0 + wm * 64 + mt * 16 + lhi * 4;
                int bb = m0 >> 10, nq0 = m0 & 1023;
                bf16x4 pk = { (__bf16)(acc[mt][nt][0] + bias), (__bf16)(acc[mt][nt][1] + bias),
                              (__bf16)(acc[mt][nt][2] + bias), (__bf16)(acc[mt][nt][3] + bias) };
                *(bf16x4*)(Vt + ((long)(bb * NH + h) * DP + d) * NSEQ + nq0) = pk;
            }
        } else {
            __bf16* dst = (sec == 0) ? Qp : Kp;
            float scl = (sec == 0) ? QSCALE : 1.0f;
            #pragma unroll
            for (int mt = 0; mt < 4; ++mt) {
                #pragma unroll
                for (int r = 0; r < 4; ++r) {
                    int m = (int)rowA0 + wm * 64 + mt * 16 + lhi * 4 + r;
                    int bb = m >> 10, nq = m & 1023;
                    long bhn = (long)(bb * NH + h) * NSEQ + nq;
                    dst[bhn * DP + d] = (__bf16)((acc[mt][nt][r] + bias) * scl);
                }
            }
        }
    }
}

// ---------------- flash attention v11 (round-14 proven version) ----------------
// 512 blocks x 8 waves, one 16-row q-set per wave -> 2 independent blocks/CU.
// K AND V double-buffered -> ONE raw barrier per iteration. All LDS read/write
// and staging offsets precomputed; kb-loop unrolled x2 so buf is compile-time.
// exp2 via single v_exp_f32. LDS: K0 [0,16K) K1 [16K,32K) ; V0 [32K,44K)
// V1 [44K,56K) ; P [56K,72K) = 2 KB/wave.

__global__ __launch_bounds__(512, 4) void flash_kernel(
    const __bf16* __restrict__ Qp, const __bf16* __restrict__ Kp,
    const __bf16* __restrict__ Vt, __bf16* __restrict__ atto)
{
    __shared__ char lds[73728];
    const int tid  = threadIdx.x;
    const int wave = tid >> 6, lane = tid & 63;
    const int lhi = lane >> 4, llo = lane & 15;

    // chunked XCD swizzle (512 = 8 XCD x 64): XCD i owns bh in [i*8,(i+1)*8)
    int lin = blockIdx.x;
    int v   = ((lin & 7) << 6) + (lin >> 3);
    const int qx = v & 7;          // q-chunk of 128 rows
    const int bh = v >> 3;

    const __bf16* Qb  = Qp + (long)bh * NSEQ * DP;
    const char*   KbB = (const char*)(Kp + (long)bh * NSEQ * DP);
    const char*   VbB = (const char*)(Vt + (long)bh * DP * NSEQ);

    char* P = lds + 57344 + wave * 2048;
    const int q0 = qx * 128 + wave * 16;

    // ---- precomputed staging offsets (loop-invariant) ----
    long soK[2]; int ldK[2];
    #pragma unroll
    for (int j = 0; j < 2; ++j) {
        int bk  = wave * 2 + j;                 // 16 x 1KB chunks
        int key = bk * 4 + (lane >> 4);         // LDS row (256 B each)
        int c   = (lane & 15) * 16;             // byte slot within row
        soK[j] = (long)key * 192 + (c ^ ((key & 15) << 4));
        ldK[j] = bk * 1024;
    }
    const int dv1 = wave * 8 + (lane >> 3);
    const int cV  = (lane & 7) * 16;
    const long soV1 = (long)dv1 * 2048 + (cV ^ ((dv1 & 7) << 4));
    const int dv2 = 64 + wave * 8 + (lane >> 3);
    const long soV2 = (long)dv2 * 2048 + (cV ^ ((dv2 & 7) << 4));
    const int ldV1 = wave * 1024, ldV2 = 8192 + wave * 1024;

    // ---- precomputed LDS read/write byte-offsets (loop-invariant) ----
    int kro[4][3], vro[2][5], pwo[4], pro[2];
    #pragma unroll
    for (int ct = 0; ct < 4; ++ct)
        #pragma unroll
        for (int dc = 0; dc < 3; ++dc)
            kro[ct][dc] = ((ct * 16 + llo) * 256 + dc * 64 + lhi * 16) ^ ((llo & 15) << 4);
    #pragma unroll
    for (int nc = 0; nc < 2; ++nc)
        #pragma unroll
        for (int t = 0; t < 5; ++t)
            vro[nc][t] = ((t * 16 + llo) * 128 + nc * 64 + lhi * 16) ^ ((llo & 7) << 4);
    #pragma unroll
    for (int ct = 0; ct < 4; ++ct)
        pwo[ct] = (llo * 128 + ct * 32 + lhi * 8) ^ ((llo & 7) << 4);
    #pragma unroll
    for (int nc = 0; nc < 2; ++nc)
        pro[nc] = (llo * 128 + nc * 64 + lhi * 16) ^ ((llo & 7) << 4);

    auto stageK = [&](int kt, int kbuf) {
        #pragma unroll
        for (int j = 0; j < 2; ++j)
            gl_lds16(KbB + kt * 12288 + soK[j], lds + kbuf * 16384 + ldK[j]);
    };
    auto stageV = [&](int kt, int vb) {
        gl_lds16(VbB + soV1 + kt * 128, lds + 32768 + vb * 12288 + ldV1);
        if (wave < 4)
            gl_lds16(VbB + soV2 + kt * 128, lds + 32768 + vb * 12288 + ldV2);
    };

    // Q fragments (B operand): Q[q][d = dc*32 + lhi*8 + j]; QSCALE folded
    bf16x8 aq[3];
    #pragma unroll
    for (int dc = 0; dc < 3; ++dc)
        aq[dc] = *(const bf16x8*)(Qb + (long)(q0 + llo) * DP + dc * 32 + lhi * 8);

    float mr = -3.0e38f, lr = 0.f;     // per-lane state for q = q0 + llo
    f32x4 acc[5];
    #pragma unroll
    for (int t = 0; t < 5; ++t) acc[t] = (f32x4){0.f, 0.f, 0.f, 0.f};

    // prologue: tile 0 into buffers 0
    stageK(0, 0);
    stageV(0, 0);
    asm volatile("s_waitcnt vmcnt(0)" ::: "memory");
    RAW_BAR();

    #pragma unroll 2
    for (int kb = 0; kb < 16; ++kb) {
        const int buf = kb & 1;
        if (kb < 15) {                              // lands during this iter's compute
            stageK(kb + 1, buf ^ 1);
            stageV(kb + 1, buf ^ 1);
        }

        // S^T = mfma(K, Q): s[ct][r] = S[q=llo][key=ct*16+lhi*4+r]
        f32x4 s[4];
        __builtin_amdgcn_s_setprio(1);
        #pragma unroll
        for (int ct = 0; ct < 4; ++ct) {
            f32x4 z = (f32x4){0.f, 0.f, 0.f, 0.f};
            #pragma unroll
            for (int dc = 0; dc < 3; ++dc) {
                bf16x8 kf = *(const bf16x8*)(lds + buf * 16384 + kro[ct][dc]);
                z = __builtin_amdgcn_mfma_f32_16x16x32_bf16(kf, aq[dc], z, 0, 0, 0);
            }
            s[ct] = z;
        }
        __builtin_amdgcn_s_setprio(0);

        // ---- online softmax (exp2 domain, lane-local row q=llo) ----
        float m0 = fmaxf(fmaxf(s[0][0], s[0][1]), fmaxf(s[0][2], s[0][3]));
        float m1 = fmaxf(fmaxf(s[1][0], s[1][1]), fmaxf(s[1][2], s[1][3]));
        float m2 = fmaxf(fmaxf(s[2][0], s[2][1]), fmaxf(s[2][2], s[2][3]));
        float m3 = fmaxf(fmaxf(s[3][0], s[3][1]), fmaxf(s[3][2], s[3][3]));
        float mx = fmaxf(fmaxf(m0, m1), fmaxf(m2, m3));
        mx = fmaxf(mx, __shfl_xor(mx, 16, 64));
        mx = fmaxf(mx, __shfl_xor(mx, 32, 64));
        if (!__all(mx <= mr + 8.0f)) {             // T13 defer-max
            float mn = fmaxf(mr, mx);
            float al = fast_exp2(mr - mn);
            mr = mn;
            lr *= al;
            #pragma unroll
            for (int t = 0; t < 5; ++t)
                #pragma unroll
                for (int r = 0; r < 4; ++r) acc[t][r] *= al;
        }
        float p[4][4]; float sm = 0.f;
        #pragma unroll
        for (int ct = 0; ct < 4; ++ct)
            #pragma unroll
            for (int r = 0; r < 4; ++r) { p[ct][r] = fast_exp2(s[ct][r] - mr); sm += p[ct][r]; }
        sm += __shfl_xor(sm, 16, 64);
        sm += __shfl_xor(sm, 32, 64);
        lr += sm;
        #pragma unroll
        for (int ct = 0; ct < 4; ++ct) {
            bf16x4 pk = { (__bf16)p[ct][0], (__bf16)p[ct][1], (__bf16)p[ct][2], (__bf16)p[ct][3] };
            *(bf16x4*)(P + pwo[ct]) = pk;
        }
        asm volatile("s_waitcnt lgkmcnt(0)" ::: "memory");

        // PV flipped: A = V^T frag (row=d), B = P frag (col=q) -> O[q=llo][d]
        __builtin_amdgcn_s_setprio(1);
        #pragma unroll
        for (int nc = 0; nc < 2; ++nc) {
            bf16x8 pP = *(const bf16x8*)(P + pro[nc]);
            #pragma unroll
            for (int t = 0; t < 5; ++t) {
                bf16x8 bv = *(const bf16x8*)(lds + 32768 + buf * 12288 + vro[nc][t]);
                acc[t] = __builtin_amdgcn_mfma_f32_16x16x32_bf16(bv, pP, acc[t], 0, 0, 0);
            }
        }
        __builtin_amdgcn_s_setprio(0);

        if (kb < 15) asm volatile("s_waitcnt vmcnt(0)" ::: "memory");  // own stages landed
        RAW_BAR();
    }

    // epilogue: per-lane q=llo; d = t*16 + lhi*4 + r -> bf16x4 8B stores
    const float linv = 1.f / lr;
    const int b = bh >> 4, h = bh & 15;
    const int q = q0 + llo;
    __bf16* outP = atto + (long)(b * NSEQ + q) * HID + h * HD;
    #pragma unroll
    for (int t = 0; t < 5; ++t) {
        int d0 = t * 16 + lhi * 4;
        if (d0 < HD) {
            bf16x4 o = { (__bf16)(acc[t][0] * linv), (__bf16)(acc[t][1] * linv),
                         (__bf16)(acc[t][2] * linv), (__bf16)(acc[t][3] * linv) };
            *(bf16x4*)(outP + d0) = o;
        }
    }
}

// ---------------- GEMM 2: out = atto @ w_out + b_out (fp32 out) ----------------
// BM=128: grid 160 blocks (32 M-tiles x 5 N-tiles, N padded 1152->1280)

__global__ __launch_bounds__(512, 4) void gemm_out_kernel(
    const __bf16* __restrict__ atto, const __bf16* __restrict__ woutT,
    const float* __restrict__ b_out, float* __restrict__ out)
{
    __shared__ char lds[24576];
    f32x4 acc[4][4];
    #pragma unroll
    for (int i = 0; i < 4; ++i)
        #pragma unroll
        for (int j = 0; j < 4; ++j) acc[i][j] = (f32x4){0.f, 0.f, 0.f, 0.f};

    // bijective chunked XCD swizzle: 160 blocks, 20 per XCD (4 bx x 5 by)
    int lin = blockIdx.x;
    int v   = (lin & 7) * 20 + (lin >> 3);
    int bx  = v / 5, by = v - bx * 5;
    long rowA0 = (long)bx * 128, rowB0 = (long)by * 256;

    gemm_core<4>(atto, woutT, HID, HID, HID / 32, rowA0, rowB0, lds, acc);

    const int wave = threadIdx.x >> 6, lane = threadIdx.x & 63;
    const int wm = wave >> 2, wn = wave & 3, lhi = lane >> 4, llo = lane & 15;

    #pragma unroll
    for (int nt = 0; nt < 4; ++nt) {
        int n = (int)rowB0 + wn * 64 + nt * 16 + llo;   // 0..1279
        if (n >= HID) continue;
        float bias = b_out[n];
        #pragma unroll
        for (int mt = 0; mt < 4; ++mt) {
            #pragma unroll
            for (int r = 0; r < 4; ++r) {
                int m = (int)rowA0 + wm * 64 + mt * 16 + lhi * 4 + r;
                out[(long)m * HID + n] = acc[mt][nt][r] + bias;
            }
        }
    }
}

// ---------------- launch ----------------

extern "C" void kernel_launch(void* const* d_in, const int* in_sizes, int n_in,
                              void* d_out, int out_size, void* d_ws, size_t ws_size,
                              hipStream_t stream) {
    const float* x      = (const float*)d_in[0];
    const float* w_qkv  = (const float*)d_in[1];
    const float* b_qkv  = (const float*)d_in[2];
    const float* w_out  = (const float*)d_in[3];
    const float* b_out  = (const float*)d_in[4];
    float* out = (float*)d_out;
    char* ws = (char*)d_ws;

    __bf16* xb    = (__bf16*)(ws + XB_OFF);
    __bf16* atto  = (__bf16*)(ws + XB_OFF);     // aliases xb (dead after gemm_qkv)
    __bf16* wqkvT = (__bf16*)(ws + WQKVT_OFF);
    __bf16* woutT = (__bf16*)(ws + WOUTT_OFF);
    __bf16* Qp    = (__bf16*)(ws + QP_OFF);
    __bf16* Kp    = (__bf16*)(ws + KP_OFF);
    __bf16* Vt    = (__bf16*)(ws + VT_OFF);

    prep_kernel<<<10688, 256, 0, stream>>>(x, xb, w_qkv, wqkvT, w_out, woutT, Qp, Kp, Vt);
    gemm_qkv_kernel<<<448, 512, 0, stream>>>(xb, wqkvT, b_qkv, Qp, Kp, Vt);
    flash_kernel<<<512, 512, 0, stream>>>(Qp, Kp, Vt, atto);
    gemm_out_kernel<<<160, 512, 0, stream>>>(atto, woutT, b_out, out);
}

// Round 18
// 118.297 us; speedup vs baseline: 1.4264x; 1.4264x over previous
//
#include <hip/hip_runtime.h>
#include <cstdint>

// Problem constants
#define NB 4
#define NSEQ 1024
#define NH 16
#define HD 72
#define HID 1152
#define QKV3 3456
#define DP 96           // padded head dim (multiple of 32 for K=32 MFMA)
// scale = 72^-0.5 folded with log2(e) so softmax runs in exp2 domain
#define QSCALE 0.17003713711193175f

typedef __attribute__((ext_vector_type(8))) __bf16 bf16x8;
typedef __attribute__((ext_vector_type(4))) __bf16 bf16x4;
typedef __attribute__((ext_vector_type(4))) float f32x4;

#define AS1 __attribute__((address_space(1)))
#define AS3 __attribute__((address_space(3)))

__device__ __forceinline__ void gl_lds16(const void* g, void* l) {
    // async global->LDS, 16B per lane; LDS dest = wave-uniform base + lane*16
    __builtin_amdgcn_global_load_lds((const AS1 uint32_t*)g, (AS3 uint32_t*)l, 16, 0, 0);
}

// raw barrier: no compiler-inserted vmcnt(0) drain (unlike __syncthreads)
#define RAW_BAR() asm volatile("s_barrier" ::: "memory")

// bare hardware 2^x (single v_exp_f32; libm exp2f is a multi-instr fixup seq)
__device__ __forceinline__ float fast_exp2(float x) {
    float r;
    asm("v_exp_f32 %0, %1" : "=v"(r) : "v"(x));
    return r;
}

// Workspace layout (bytes)
#define XB_OFF     0UL           // x as bf16 [4096][1152]; ALIASED as atto after gemm_qkv
#define WQKVT_OFF  9437184UL     // w_qkv^T bf16  [3584][1152] (rows 3456+ junk, unused)
#define WOUTT_OFF  17694720UL    // w_out^T bf16  [1280][1152] (rows 1152+ junk, unused)
#define QP_OFF     20643840UL    // Q padded bf16 [64][1024][96] (QSCALE folded)
#define KP_OFF     33226752UL    // K padded bf16 [64][1024][96]
#define VT_OFF     45809664UL    // V^T padded bf16 [64][96][1024]
// total: 58,392,576 bytes

// ---------------- fused prep kernel ----------------
// blocks [0,4608):      x fp32 -> bf16 (float4/thread)
// blocks [4608,8496):   w_qkv [1152][3456] -> wqkvT bf16 (32x32 tiles)
// blocks [8496,9792):   w_out [1152][1152] -> woutT bf16
// blocks [9792,10688):  zero d=72..95 pad regions of Qp/Kp/Vt

__global__ void prep_kernel(const float* __restrict__ x, __bf16* __restrict__ xb,
                            const float* __restrict__ w_qkv, __bf16* __restrict__ wqkvT,
                            const float* __restrict__ w_out, __bf16* __restrict__ woutT,
                            __bf16* __restrict__ Qp, __bf16* __restrict__ Kp,
                            __bf16* __restrict__ Vt) {
    __shared__ float t[32][33];
    const int blk = blockIdx.x, tid = threadIdx.x;
    if (blk < 4608) {
        long i = (long)blk * 256 + tid;
        float4 v = ((const float4*)x)[i];
        bf16x4 o = { (__bf16)v.x, (__bf16)v.y, (__bf16)v.z, (__bf16)v.w };
        ((bf16x4*)xb)[i] = o;
    } else if (blk < 9792) {
        const float* in;  __bf16* outp;  int Nc, K, n0, k0;
        if (blk < 8496) {
            int b = blk - 4608; in = w_qkv; outp = wqkvT; Nc = QKV3; K = HID;
            n0 = (b % 108) * 32; k0 = (b / 108) * 32;
        } else {
            int b = blk - 8496; in = w_out; outp = woutT; Nc = HID; K = HID;
            n0 = (b % 36) * 32; k0 = (b / 36) * 32;
        }
        int xx = tid & 31, yy = tid >> 5;
        #pragma unroll
        for (int i = 0; i < 32; i += 8)
            t[yy + i][xx] = in[(long)(k0 + yy + i) * Nc + n0 + xx];
        __syncthreads();
        #pragma unroll
        for (int i = 0; i < 32; i += 8)
            outp[(long)(n0 + yy + i) * K + k0 + xx] = (__bf16)t[xx][yy + i];
    } else {
        int i = (blk - 9792) * 256 + tid;            // 0..229375
        uint4 z = make_uint4(0u, 0u, 0u, 0u);
        if (i < 131072) {
            __bf16* base = (i & 65536) ? Kp : Qp;
            int row = i & 65535;
            uint4* p = (uint4*)(base + row * 96 + 72);   // 48 B pad per row
            p[0] = z; p[1] = z; p[2] = z;
        } else {
            int j = i - 131072;                          // 0..98303
            int bh = j / 1536, w = j - bh * 1536;
            *((uint4*)(Vt + (long)bh * 98304 + 73728) + w) = z;
        }
    }
}

// ---------------- GEMM engine (round-11/14/16 proven version) ----------------
// TRIPLE-buffered LDS, global_load_lds staging 2 tiles ahead, counted vmcnt(L)
// at tile boundary (never drained to 0 in steady state), raw s_barrier once
// per tile, T2 XOR swizzle with pre-swizzled global source, T5 setprio.
// Runtime buffer index, #pragma unroll 1.
// DO NOT revisit: unroll-3 (r12, schedule bloat), B-in-registers with
// launch_bounds(512,6) (r15, acc spill -> 602MB scratch), B-in-registers with
// (512,4) (r17, per-wave L2 latency exposed -> MfmaUtil 16%). This LDS-both-
// operands structure at 48us/29% MfmaUtil is the proven local optimum.

template<int MT>   // m-fragments per wave; BM = MT*32 (4 -> 128)
__device__ __forceinline__ void gemm_core(
    const __bf16* __restrict__ A, const __bf16* __restrict__ Bt,
    int lda, int ldb, int ntk, long rowA0, long rowB0,
    char* lds, f32x4 acc[MT][4])
{
    constexpr int BM    = MT * 32;
    constexpr int ATILE = BM * 64;        // bytes (rows of 64 B)
    constexpr int TILE  = ATILE + 256 * 64;
    constexpr int L     = BM / 128 + 2;   // gl_lds per thread per tile (=3)

    const int tid  = threadIdx.x;
    const int wave = tid >> 6, lane = tid & 63;
    const int wm = wave >> 2, wn = wave & 3;      // 2 x 4 wave grid
    const int lhi = lane >> 4, llo = lane & 15;
    const int srow = tid >> 2;                    // staging row (0..127)
    const int scol = (tid & 3) * 8;               // staging col element

    auto stage = [&](int kt, int buf) {
        char* base = lds + buf * TILE;
        #pragma unroll
        for (int j = 0; j < BM / 128; ++j) {
            int r  = srow + j * 128;
            int ks = scol ^ ((((unsigned)r >> 1) & 3) << 3);   // pre-swizzled source
            gl_lds16(A + (rowA0 + r) * (long)lda + kt * 32 + ks, base + tid * 16 + j * 8192);
        }
        #pragma unroll
        for (int j = 0; j < 2; ++j) {
            int r  = srow + j * 128;
            int ks = scol ^ ((((unsigned)r >> 1) & 3) << 3);
            gl_lds16(Bt + (rowB0 + r) * (long)ldb + kt * 32 + ks,
                     base + ATILE + tid * 16 + j * 8192);
        }
    };

    stage(0, 0);
    stage(1, 1);
    asm volatile("s_waitcnt vmcnt(%0)" :: "n"(L) : "memory");   // tile0 landed
    RAW_BAR();

    int buf = 0;
    #pragma unroll 1
    for (int t = 0; t < ntk; ++t) {
        char* Ab = lds + buf * TILE;
        char* Bb = Ab + ATILE;
        int nb = buf + 2; if (nb >= 3) nb -= 3;
        if (t + 2 < ntk) stage(t + 2, nb);        // issue 2 tiles ahead

        bf16x8 bfr[4];
        #pragma unroll
        for (int nt = 0; nt < 4; ++nt) {
            int R = wn * 64 + nt * 16 + llo;
            int b = (R * 64 + lhi * 16) ^ ((((unsigned)R >> 1) & 3) << 4);
            bfr[nt] = *(const bf16x8*)(Bb + b);
        }
        bf16x8 af[MT / 2];
        #pragma unroll
        for (int mt = 0; mt < MT / 2; ++mt) {
            int R = wm * (BM / 2) + mt * 16 + llo;
            int b = (R * 64 + lhi * 16) ^ ((((unsigned)R >> 1) & 3) << 4);
            af[mt] = *(const bf16x8*)(Ab + b);
        }
        __builtin_amdgcn_s_setprio(1);
        #pragma unroll
        for (int mt = 0; mt < MT / 2; ++mt)
            #pragma unroll
            for (int nt = 0; nt < 4; ++nt)
                acc[mt][nt] = __builtin_amdgcn_mfma_f32_16x16x32_bf16(af[mt], bfr[nt], acc[mt][nt], 0, 0, 0);
        __builtin_amdgcn_s_setprio(0);
        #pragma unroll
        for (int mt = 0; mt < MT / 2; ++mt) {
            int R = wm * (BM / 2) + (MT / 2 + mt) * 16 + llo;
            int b = (R * 64 + lhi * 16) ^ ((((unsigned)R >> 1) & 3) << 4);
            af[mt] = *(const bf16x8*)(Ab + b);
        }
        __builtin_amdgcn_s_setprio(1);
        #pragma unroll
        for (int mt = 0; mt < MT / 2; ++mt)
            #pragma unroll
            for (int nt = 0; nt < 4; ++nt)
                acc[MT / 2 + mt][nt] = __builtin_amdgcn_mfma_f32_16x16x32_bf16(af[mt], bfr[nt], acc[MT / 2 + mt][nt], 0, 0, 0);
        __builtin_amdgcn_s_setprio(0);
        // boundary: wait until only t+2's L loads remain -> t+1 resident
        if (t + 2 < ntk)      asm volatile("s_waitcnt vmcnt(%0)" :: "n"(L) : "memory");
        else if (t + 1 < ntk) asm volatile("s_waitcnt vmcnt(0)" ::: "memory");
        RAW_BAR();
        buf = (buf == 2) ? 0 : buf + 1;
    }
}

// ---------------- GEMM 1: qkv = x @ w_qkv + b, scatter to Qp/Kp/Vt ----------------
// BM=128: grid 448 blocks (32 M-tiles x 14 N-tiles, N padded 3456->3584)

__global__ __launch_bounds__(512, 4) void gemm_qkv_kernel(
    const __bf16* __restrict__ xb, const __bf16* __restrict__ wqkvT,
    const float* __restrict__ b_qkv,
    __bf16* __restrict__ Qp, __bf16* __restrict__ Kp, __bf16* __restrict__ Vt)
{
    __shared__ char lds[73728];
    f32x4 acc[4][4];
    #pragma unroll
    for (int i = 0; i < 4; ++i)
        #pragma unroll
        for (int j = 0; j < 4; ++j) acc[i][j] = (f32x4){0.f, 0.f, 0.f, 0.f};

    // bijective 2D-chunked XCD swizzle: each XCD owns an 8bx x 7by rectangle
    int lin = blockIdx.x;
    int xcd = lin & 7, l = lin >> 3;              // l in [0,56)
    int lbx = l / 7;
    int bx  = (xcd & 3) * 8 + lbx;                // 0..31
    int by  = (xcd >> 2) * 7 + (l - lbx * 7);     // 0..13
    long rowA0 = (long)bx * 128, rowB0 = (long)by * 256;

    gemm_core<4>(xb, wqkvT, HID, HID, HID / 32, rowA0, rowB0, lds, acc);

    const int wave = threadIdx.x >> 6, lane = threadIdx.x & 63;
    const int wm = wave >> 2, wn = wave & 3, lhi = lane >> 4, llo = lane & 15;

    #pragma unroll
    for (int nt = 0; nt < 4; ++nt) {
        int n = (int)rowB0 + wn * 64 + nt * 16 + llo;   // 0..3583
        if (n >= QKV3) continue;
        int sec = n / HID;
        int nn  = n - sec * HID;
        int h   = nn / HD;
        int d   = nn - h * HD;
        float bias = b_qkv[n];
        if (sec == 2) {
            // V: r-quad is nq-contiguous -> one 8B bf16x4 store per mt
            #pragma unroll
            for (int mt = 0; mt < 4; ++mt) {
                int m0 = (int)rowA0 + wm * 64 + mt * 16 + lhi * 4;
                int bb = m0 >> 10, nq0 = m0 & 1023;
                bf16x4 pk = { (__bf16)(acc[mt][nt][0] + bias), (__bf16)(acc[mt][nt][1] + bias),
                              (__bf16)(acc[mt][nt][2] + bias), (__bf16)(acc[mt][nt][3] + bias) };
                *(bf16x4*)(Vt + ((long)(bb * NH + h) * DP + d) * NSEQ + nq0) = pk;
            }
        } else {
            __bf16* dst = (sec == 0) ? Qp : Kp;
            float scl = (sec == 0) ? QSCALE : 1.0f;
            #pragma unroll
            for (int mt = 0; mt < 4; ++mt) {
                #pragma unroll
                for (int r = 0; r < 4; ++r) {
                    int m = (int)rowA0 + wm * 64 + mt * 16 + lhi * 4 + r;
                    int bb = m >> 10, nq = m & 1023;
                    long bhn = (long)(bb * NH + h) * NSEQ + nq;
                    dst[bhn * DP + d] = (__bf16)((acc[mt][nt][r] + bias) * scl);
                }
            }
        }
    }
}

// ---------------- flash attention v11 (round-14/16 proven version) ----------------
// 512 blocks x 8 waves, one 16-row q-set per wave -> 2 independent blocks/CU.
// K AND V double-buffered -> ONE raw barrier per iteration. All LDS read/write
// and staging offsets precomputed; kb-loop unrolled x2 so buf is compile-time.
// exp2 via single v_exp_f32. LDS: K0 [0,16K) K1 [16K,32K) ; V0 [32K,44K)
// V1 [44K,56K) ; P [56K,72K) = 2 KB/wave.

__global__ __launch_bounds__(512, 4) void flash_kernel(
    const __bf16* __restrict__ Qp, const __bf16* __restrict__ Kp,
    const __bf16* __restrict__ Vt, __bf16* __restrict__ atto)
{
    __shared__ char lds[73728];
    const int tid  = threadIdx.x;
    const int wave = tid >> 6, lane = tid & 63;
    const int lhi = lane >> 4, llo = lane & 15;

    // chunked XCD swizzle (512 = 8 XCD x 64): XCD i owns bh in [i*8,(i+1)*8)
    int lin = blockIdx.x;
    int v   = ((lin & 7) << 6) + (lin >> 3);
    const int qx = v & 7;          // q-chunk of 128 rows
    const int bh = v >> 3;

    const __bf16* Qb  = Qp + (long)bh * NSEQ * DP;
    const char*   KbB = (const char*)(Kp + (long)bh * NSEQ * DP);
    const char*   VbB = (const char*)(Vt + (long)bh * DP * NSEQ);

    char* P = lds + 57344 + wave * 2048;
    const int q0 = qx * 128 + wave * 16;

    // ---- precomputed staging offsets (loop-invariant) ----
    long soK[2]; int ldK[2];
    #pragma unroll
    for (int j = 0; j < 2; ++j) {
        int bk  = wave * 2 + j;                 // 16 x 1KB chunks
        int key = bk * 4 + (lane >> 4);         // LDS row (256 B each)
        int c   = (lane & 15) * 16;             // byte slot within row
        soK[j] = (long)key * 192 + (c ^ ((key & 15) << 4));
        ldK[j] = bk * 1024;
    }
    const int dv1 = wave * 8 + (lane >> 3);
    const int cV  = (lane & 7) * 16;
    const long soV1 = (long)dv1 * 2048 + (cV ^ ((dv1 & 7) << 4));
    const int dv2 = 64 + wave * 8 + (lane >> 3);
    const long soV2 = (long)dv2 * 2048 + (cV ^ ((dv2 & 7) << 4));
    const int ldV1 = wave * 1024, ldV2 = 8192 + wave * 1024;

    // ---- precomputed LDS read/write byte-offsets (loop-invariant) ----
    int kro[4][3], vro[2][5], pwo[4], pro[2];
    #pragma unroll
    for (int ct = 0; ct < 4; ++ct)
        #pragma unroll
        for (int dc = 0; dc < 3; ++dc)
            kro[ct][dc] = ((ct * 16 + llo) * 256 + dc * 64 + lhi * 16) ^ ((llo & 15) << 4);
    #pragma unroll
    for (int nc = 0; nc < 2; ++nc)
        #pragma unroll
        for (int t = 0; t < 5; ++t)
            vro[nc][t] = ((t * 16 + llo) * 128 + nc * 64 + lhi * 16) ^ ((llo & 7) << 4);
    #pragma unroll
    for (int ct = 0; ct < 4; ++ct)
        pwo[ct] = (llo * 128 + ct * 32 + lhi * 8) ^ ((llo & 7) << 4);
    #pragma unroll
    for (int nc = 0; nc < 2; ++nc)
        pro[nc] = (llo * 128 + nc * 64 + lhi * 16) ^ ((llo & 7) << 4);

    auto stageK = [&](int kt, int kbuf) {
        #pragma unroll
        for (int j = 0; j < 2; ++j)
            gl_lds16(KbB + kt * 12288 + soK[j], lds + kbuf * 16384 + ldK[j]);
    };
    auto stageV = [&](int kt, int vb) {
        gl_lds16(VbB + soV1 + kt * 128, lds + 32768 + vb * 12288 + ldV1);
        if (wave < 4)
            gl_lds16(VbB + soV2 + kt * 128, lds + 32768 + vb * 12288 + ldV2);
    };

    // Q fragments (B operand): Q[q][d = dc*32 + lhi*8 + j]; QSCALE folded
    bf16x8 aq[3];
    #pragma unroll
    for (int dc = 0; dc < 3; ++dc)
        aq[dc] = *(const bf16x8*)(Qb + (long)(q0 + llo) * DP + dc * 32 + lhi * 8);

    float mr = -3.0e38f, lr = 0.f;     // per-lane state for q = q0 + llo
    f32x4 acc[5];
    #pragma unroll
    for (int t = 0; t < 5; ++t) acc[t] = (f32x4){0.f, 0.f, 0.f, 0.f};

    // prologue: tile 0 into buffers 0
    stageK(0, 0);
    stageV(0, 0);
    asm volatile("s_waitcnt vmcnt(0)" ::: "memory");
    RAW_BAR();

    #pragma unroll 2
    for (int kb = 0; kb < 16; ++kb) {
        const int buf = kb & 1;
        if (kb < 15) {                              // lands during this iter's compute
            stageK(kb + 1, buf ^ 1);
            stageV(kb + 1, buf ^ 1);
        }

        // S^T = mfma(K, Q): s[ct][r] = S[q=llo][key=ct*16+lhi*4+r]
        f32x4 s[4];
        __builtin_amdgcn_s_setprio(1);
        #pragma unroll
        for (int ct = 0; ct < 4; ++ct) {
            f32x4 z = (f32x4){0.f, 0.f, 0.f, 0.f};
            #pragma unroll
            for (int dc = 0; dc < 3; ++dc) {
                bf16x8 kf = *(const bf16x8*)(lds + buf * 16384 + kro[ct][dc]);
                z = __builtin_amdgcn_mfma_f32_16x16x32_bf16(kf, aq[dc], z, 0, 0, 0);
            }
            s[ct] = z;
        }
        __builtin_amdgcn_s_setprio(0);

        // ---- online softmax (exp2 domain, lane-local row q=llo) ----
        float m0 = fmaxf(fmaxf(s[0][0], s[0][1]), fmaxf(s[0][2], s[0][3]));
        float m1 = fmaxf(fmaxf(s[1][0], s[1][1]), fmaxf(s[1][2], s[1][3]));
        float m2 = fmaxf(fmaxf(s[2][0], s[2][1]), fmaxf(s[2][2], s[2][3]));
        float m3 = fmaxf(fmaxf(s[3][0], s[3][1]), fmaxf(s[3][2], s[3][3]));
        float mx = fmaxf(fmaxf(m0, m1), fmaxf(m2, m3));
        mx = fmaxf(mx, __shfl_xor(mx, 16, 64));
        mx = fmaxf(mx, __shfl_xor(mx, 32, 64));
        if (!__all(mx <= mr + 8.0f)) {             // T13 defer-max
            float mn = fmaxf(mr, mx);
            float al = fast_exp2(mr - mn);
            mr = mn;
            lr *= al;
            #pragma unroll
            for (int t = 0; t < 5; ++t)
                #pragma unroll
                for (int r = 0; r < 4; ++r) acc[t][r] *= al;
        }
        float p[4][4]; float sm = 0.f;
        #pragma unroll
        for (int ct = 0; ct < 4; ++ct)
            #pragma unroll
            for (int r = 0; r < 4; ++r) { p[ct][r] = fast_exp2(s[ct][r] - mr); sm += p[ct][r]; }
        sm += __shfl_xor(sm, 16, 64);
        sm += __shfl_xor(sm, 32, 64);
        lr += sm;
        #pragma unroll
        for (int ct = 0; ct < 4; ++ct) {
            bf16x4 pk = { (__bf16)p[ct][0], (__bf16)p[ct][1], (__bf16)p[ct][2], (__bf16)p[ct][3] };
            *(bf16x4*)(P + pwo[ct]) = pk;
        }
        asm volatile("s_waitcnt lgkmcnt(0)" ::: "memory");

        // PV flipped: A = V^T frag (row=d), B = P frag (col=q) -> O[q=llo][d]
        __builtin_amdgcn_s_setprio(1);
        #pragma unroll
        for (int nc = 0; nc < 2; ++nc) {
            bf16x8 pP = *(const bf16x8*)(P + pro[nc]);
            #pragma unroll
            for (int t = 0; t < 5; ++t) {
                bf16x8 bv = *(const bf16x8*)(lds + 32768 + buf * 12288 + vro[nc][t]);
                acc[t] = __builtin_amdgcn_mfma_f32_16x16x32_bf16(bv, pP, acc[t], 0, 0, 0);
            }
        }
        __builtin_amdgcn_s_setprio(0);

        if (kb < 15) asm volatile("s_waitcnt vmcnt(0)" ::: "memory");  // own stages landed
        RAW_BAR();
    }

    // epilogue: per-lane q=llo; d = t*16 + lhi*4 + r -> bf16x4 8B stores
    const float linv = 1.f / lr;
    const int b = bh >> 4, h = bh & 15;
    const int q = q0 + llo;
    __bf16* outP = atto + (long)(b * NSEQ + q) * HID + h * HD;
    #pragma unroll
    for (int t = 0; t < 5; ++t) {
        int d0 = t * 16 + lhi * 4;
        if (d0 < HD) {
            bf16x4 o = { (__bf16)(acc[t][0] * linv), (__bf16)(acc[t][1] * linv),
                         (__bf16)(acc[t][2] * linv), (__bf16)(acc[t][3] * linv) };
            *(bf16x4*)(outP + d0) = o;
        }
    }
}

// ---------------- GEMM 2: out = atto @ w_out + b_out (fp32 out) ----------------
// BM=128: grid 160 blocks (32 M-tiles x 5 N-tiles, N padded 1152->1280)

__global__ __launch_bounds__(512, 4) void gemm_out_kernel(
    const __bf16* __restrict__ atto, const __bf16* __restrict__ woutT,
    const float* __restrict__ b_out, float* __restrict__ out)
{
    __shared__ char lds[73728];
    f32x4 acc[4][4];
    #pragma unroll
    for (int i = 0; i < 4; ++i)
        #pragma unroll
        for (int j = 0; j < 4; ++j) acc[i][j] = (f32x4){0.f, 0.f, 0.f, 0.f};

    // bijective chunked XCD swizzle: 160 blocks, 20 per XCD (4 bx x 5 by)
    int lin = blockIdx.x;
    int v   = (lin & 7) * 20 + (lin >> 3);
    int bx  = v / 5, by = v - bx * 5;
    long rowA0 = (long)bx * 128, rowB0 = (long)by * 256;

    gemm_core<4>(atto, woutT, HID, HID, HID / 32, rowA0, rowB0, lds, acc);

    const int wave = threadIdx.x >> 6, lane = threadIdx.x & 63;
    const int wm = wave >> 2, wn = wave & 3, lhi = lane >> 4, llo = lane & 15;

    #pragma unroll
    for (int nt = 0; nt < 4; ++nt) {
        int n = (int)rowB0 + wn * 64 + nt * 16 + llo;   // 0..1279
        if (n >= HID) continue;
        float bias = b_out[n];
        #pragma unroll
        for (int mt = 0; mt < 4; ++mt) {
            #pragma unroll
            for (int r = 0; r < 4; ++r) {
                int m = (int)rowA0 + wm * 64 + mt * 16 + lhi * 4 + r;
                out[(long)m * HID + n] = acc[mt][nt][r] + bias;
            }
        }
    }
}

// ---------------- launch ----------------

extern "C" void kernel_launch(void* const* d_in, const int* in_sizes, int n_in,
                              void* d_out, int out_size, void* d_ws, size_t ws_size,
                              hipStream_t stream) {
    const float* x      = (const float*)d_in[0];
    const float* w_qkv  = (const float*)d_in[1];
    const float* b_qkv  = (const float*)d_in[2];
    const float* w_out  = (const float*)d_in[3];
    const float* b_out  = (const float*)d_in[4];
    float* out = (float*)d_out;
    char* ws = (char*)d_ws;

    __bf16* xb    = (__bf16*)(ws + XB_OFF);
    __bf16* atto  = (__bf16*)(ws + XB_OFF);     // aliases xb (dead after gemm_qkv)
    __bf16* wqkvT = (__bf16*)(ws + WQKVT_OFF);
    __bf16* woutT = (__bf16*)(ws + WOUTT_OFF);
    __bf16* Qp    = (__bf16*)(ws + QP_OFF);
    __bf16* Kp    = (__bf16*)(ws + KP_OFF);
    __bf16* Vt    = (__bf16*)(ws + VT_OFF);

    prep_kernel<<<10688, 256, 0, stream>>>(x, xb, w_qkv, wqkvT, w_out, woutT, Qp, Kp, Vt);
    gemm_qkv_kernel<<<448, 512, 0, stream>>>(xb, wqkvT, b_qkv, Qp, Kp, Vt);
    flash_kernel<<<512, 512, 0, stream>>>(Qp, Kp, Vt, atto);
    gemm_out_kernel<<<160, 512, 0, stream>>>(atto, woutT, b_out, out);
}